// Round 4
// baseline (451.872 us; speedup 1.0000x reference)
//
#include <hip/hip_runtime.h>
#include <math.h>

#define PS     65
#define NPIX   (PS * PS)
#define SP     40                 // S row pitch in floats (32 used + 8 pad absorbs j=-1/j=4)
#define SROWS  77                 // rows y=-6..70 mapped to ry=0..76 (pad rows read as zero)
#define SSIZE  (SROWS * SP)

// atan(t)*(4/pi) for t in [0,1], degree-9 odd minimax, |err|<=1.3e-5
#define C0  1.2730689f
#define C1 -0.4205505f
#define C2  0.2293627f
#define C3 -0.1083947f
#define C4  0.0265281f

__global__ __launch_bounds__(256) void sift_desc_kernel(
        const float* __restrict__ img, float* __restrict__ out) {
    const int s   = blockIdx.x;     // slice index in (B, C, 8, 8) row-major
    const int tid = threadIdx.x;

    // decode slice -> (b, c, tile_i, tile_j)
    const int b   = s / 192;        // C*8*8 = 192
    const int rem = s - b * 192;
    const int c   = rem >> 6;
    const int t2  = rem & 63;
    const int pi  = t2 >> 3;
    const int pj  = t2 & 7;
    const float* src = img + ((size_t)((b * 3 + c) * 520 + pi * 65)) * 520 + pj * 65;

    __shared__ float patch[NPIX];      // 65x65 tile, row stride 65 (bank = (y+x)%32: clean)
    __shared__ float S[SSIZE];         // column-pass partials: S[(y+6)*SP + j*8 + k]
    __shared__ float gtab[PS];         // normalized gaussian * sqrt(0.5)
    __shared__ float fin[128];
    __shared__ float redv[2];

    // zero S (pad rows/slots must be zero: row-pass reads pad rows unconditionally)
    for (int k = tid; k < SSIZE; k += 256) S[k] = 0.0f;

    // gaussian: sigma = 65/sqrt(2) -> 2*sigma^2 = 4225
    if (tid < PS) {
        float d = (float)(tid - 32);
        gtab[tid] = expf(-(d * d) * (1.0f / 4225.0f));
    }

    // stage patch (coalesced: 260B contiguous rows)
    for (int p = tid; p < NPIX; p += 256) {
        int y = p / 65;
        int x = p - y * 65;
        patch[p] = src[y * 520 + x];
    }
    __syncthreads();

    // normalize: fold invZ and the gradient 0.5 factor: gtab *= invZ*sqrt(0.5)
    if (tid < 64) {
        float v = gtab[tid] + ((tid == 0) ? gtab[64] : 0.0f);
        #pragma unroll
        for (int off = 32; off > 0; off >>= 1) v += __shfl_down(v, off);
        if (tid == 0) redv[0] = 0.70710678f / v;
    }
    __syncthreads();
    const float invZ = redv[0];
    if (tid < PS) gtab[tid] *= invZ;
    __syncthreads();

    // ---- main pass: work item e = (row y, x-quarter q). Lanes = different rows
    // -> every ds_add targets a distinct S row: zero atomic collisions.
    for (int e = tid; e < 260; e += 256) {
        const int y  = e >> 2;
        const int q  = e & 3;
        const int x0 = q << 4;

        const int rowb = y * 65;
        const int rowm = (y > 0  ? y - 1 : 0)  * 65;
        const int rowp = (y < 64 ? y + 1 : 64) * 65;
        const float gy_t = gtab[y];
        const int sbq = (y + 6) * SP + (q << 3);   // S base for window j=q

        float cprev = patch[rowb + ((q == 0) ? 0 : x0 - 1)];
        float ccur  = patch[rowb + x0];

#define PX_BODY(XEXPR, CNEXT_EXPR, WXA, WXB, DO_B, JO)                         \
        {                                                                      \
            const int x = (XEXPR);                                             \
            float cnext = (CNEXT_EXPR);                                        \
            float top = patch[rowm + x];                                       \
            float bot = patch[rowp + x];                                       \
            float G = cnext - cprev;          /* 2*gx */                       \
            float H = bot - top;              /* 2*gy */                       \
            float r2 = fmaf(G, G, H * H);                                      \
            float mag = sqrtf(r2) * (gy_t * gtab[x]);                          \
            float Gx = G + 2e-10f;                                             \
            float ax = fabsf(Gx), ay = fabsf(H);                               \
            float mn = fminf(ax, ay), mx = fmaxf(ax, ay);                      \
            float t1 = mn * __builtin_amdgcn_rcpf(fmaxf(mx, 1e-35f));          \
            float ss = t1 * t1;                                                \
            float u  = t1 * fmaf(ss, fmaf(ss, fmaf(ss, fmaf(ss, C4, C3), C2), C1), C0); \
            float A  = (ay > ax) ? 2.0f - u : u;                               \
            A = (Gx < 0.0f) ? 4.0f - A : A;                                    \
            A = (H  < 0.0f) ? -A : A;                                          \
            float ob = A + 8.0f;              /* in [4,12] */                  \
            float fl = truncf(ob);                                             \
            float fr = ob - fl;                                                \
            int b0 = ((int)fl) & 7;                                            \
            int b1 = (b0 + 1) & 7;                                             \
            float w1 = fr * mag;                                               \
            float w0 = mag - w1;                                               \
            int i0 = sbq + (JO) + b0;                                          \
            int i1 = sbq + (JO) + b1;                                          \
            atomicAdd(&S[i0], w0 * (WXA));                                     \
            atomicAdd(&S[i1], w1 * (WXA));                                     \
            if (DO_B) {                                                        \
                atomicAdd(&S[i0 - 8], w0 * (WXB));                             \
                atomicAdd(&S[i1 - 8], w1 * (WXB));                             \
            }                                                                  \
            cprev = ccur; ccur = cnext;                                        \
        }

        #pragma unroll
        for (int i = 0; i < 16; ++i) {
            const int   txc = (i + 6) & 15;                     // lane-uniform, static
            const float wxA = 1.0f - fabsf((float)txc - 12.5f) * (1.0f / 13.0f);
            const float wxB = (9.5f - (float)txc) * (1.0f / 13.0f);
            const bool  doB = (txc <= 9);                       // wxB > 0
            const int   jo  = ((i + 6) >> 4) << 3;              // 0 or 8
            PX_BODY(x0 + i, patch[rowb + x + 1], wxA, wxB, doB, jo)
        }
        if (q == 3) {
            // x = 64: right neighbor clamps to row[64] = ccur; tx=6, jA=4 -> pad, jB=3 real
            PX_BODY(64, ccur, 0.5f, (3.5f / 13.0f), true, 8)
        }
#undef PX_BODY
    }
    __syncthreads();

    // ---- row pass: bin = k*16 + i*4 + j reads S[(i*16 + t)*SP + j*8 + k], t=0..25
    // pad rows (ry<6, ry>70) are zero -> no bounds checks.
    if (tid < 128) {
        const int k  = tid >> 4;
        const int ii = (tid >> 2) & 3;
        const int j  = tid & 3;
        const int base = (ii * 16) * SP + (j << 3) + k;
        float v = 0.0f;
        #pragma unroll
        for (int t = 0; t < 26; ++t) {
            const float wy = (13.0f - fabsf((float)t - 12.5f)) * (1.0f / 13.0f);
            v += wy * S[base + t * SP];
        }
        fin[tid] = v;
    }
    __syncthreads();

    // first L2 norm
    if (tid < 64) {
        float sq = fin[tid] * fin[tid] + fin[tid + 64] * fin[tid + 64];
        #pragma unroll
        for (int off = 32; off > 0; off >>= 1) sq += __shfl_down(sq, off);
        if (tid == 0) redv[0] = sq;
    }
    __syncthreads();
    float inv1 = 1.0f / fmaxf(sqrtf(redv[0]), 1e-12f);
    if (tid < 128) {
        fin[tid] = fminf(fin[tid] * inv1, 0.2f);   // values non-negative; clip hi
    }
    __syncthreads();

    // second L2 norm
    if (tid < 64) {
        float sq = fin[tid] * fin[tid] + fin[tid + 64] * fin[tid + 64];
        #pragma unroll
        for (int off = 32; off > 0; off >>= 1) sq += __shfl_down(sq, off);
        if (tid == 0) redv[1] = sq;
    }
    __syncthreads();
    float inv2 = 1.0f / fmaxf(sqrtf(redv[1]), 1e-12f);
    if (tid < 128) {
        out[(size_t)s * 128 + tid] = fin[tid] * inv2;
    }
}

extern "C" void kernel_launch(void* const* d_in, const int* in_sizes, int n_in,
                              void* d_out, int out_size, void* d_ws, size_t ws_size,
                              hipStream_t stream) {
    const float* img = (const float*)d_in[0];
    float* out = (float*)d_out;
    const int B = in_sizes[0] / (3 * 520 * 520);
    const int nslices = B * 192;
    sift_desc_kernel<<<nslices, 256, 0, stream>>>(img, out);
}

// Round 5
// 103.315 us; speedup vs baseline: 4.3737x; 4.3737x over previous
//
#include <hip/hip_runtime.h>
#include <math.h>

#define PS     65
#define NPIX   (PS * PS)
#define PWP    74                 // PW pitch: cols 0..73 = x in [-6, 67] (pads zero)
#define SPIT   33                 // S pitch: 32 slots + 1 (bank spread)
#define SROWS  77                 // S rows: y+6 for y in [-6, 70] (pad rows zero)
#define SSZ    (SROWS * SPIT)     // 2541 <= NPIX, S aliases patch

// atan(t)*(4/pi) for t in [0,1], degree-9 odd minimax, |err|<=1.3e-5
#define C0  1.2730689f
#define C1 -0.4205505f
#define C2  0.2293627f
#define C3 -0.1083947f
#define C4  0.0265281f

#define QS  8388608.0f            // 2^23 fixed-point pack scale (cancels in L2 norms)

__global__ __launch_bounds__(256) void sift_desc_kernel(
        const float* __restrict__ img, float* __restrict__ out) {
    const int s   = blockIdx.x;     // slice index in (B, C, 8, 8) row-major
    const int tid = threadIdx.x;

    // decode slice -> (b, c, tile_i, tile_j)
    const int b   = s / 192;        // C*8*8 = 192
    const int rem = s - b * 192;
    const int c   = rem >> 6;
    const int t2  = rem & 63;
    const int pi  = t2 >> 3;
    const int pj  = t2 & 7;
    const float* src = img + ((size_t)((b * 3 + c) * 520 + pi * 65)) * 520 + pj * 65;

    __shared__ float patch[NPIX];                     // later aliased as S (SSZ < NPIX)
    __shared__ __align__(16) unsigned int PW[PS * PWP];
    __shared__ float gtab[PS];
    __shared__ float fin[128];
    __shared__ float redv[2];

    float* S = patch;   // reuse: patch is dead after pass 1 (barrier-separated)

    // phase 0: zero PW (pads must be 0), gaussian table, stage patch
    for (int k = tid; k < PS * PWP; k += 256) PW[k] = 0u;
    if (tid < PS) {
        float d = (float)(tid - 32);
        gtab[tid] = expf(-(d * d) * (1.0f / 4225.0f));   // sigma=65/sqrt2 -> 2s^2=4225
    }
    for (int p = tid; p < NPIX; p += 256) {
        int y = p / 65;
        int x = p - y * 65;
        patch[p] = src[y * 520 + x];
    }
    __syncthreads();

    // normalize gtab; fold sqrt(0.5) (gradient /2 factor, applied twice via gy*gx)
    if (tid < 64) {
        float v = gtab[tid] + ((tid == 0) ? gtab[64] : 0.0f);
        #pragma unroll
        for (int off = 32; off > 0; off >>= 1) v += __shfl_down(v, off);
        if (tid == 0) redv[0] = 0.70710678f / v;
    }
    __syncthreads();
    const float invZ = redv[0];
    if (tid < PS) gtab[tid] *= invZ;
    __syncthreads();

    // ---- pass 1: per-pixel math ONCE; item e = (row y, x-quarter q), sliding window
    for (int e = tid; e < 260; e += 256) {
        const int y  = e >> 2;
        const int q  = e & 3;
        const int x0 = q << 4;

        const int rowb = y * 65;
        const int rowm = (y > 0  ? y - 1 : 0)  * 65;
        const int rowp = (y < 64 ? y + 1 : 64) * 65;
        const float gy_t = gtab[y];
        const int pwb = y * PWP + 6 + x0;          // store at col x+6

        float cprev = patch[rowb + ((q == 0) ? 0 : x0 - 1)];
        float ccur  = patch[rowb + x0];

#define PX1(XEXPR, CNEXT_EXPR, PWIDX)                                          \
        {                                                                      \
            const int x = (XEXPR);                                             \
            float cnext = (CNEXT_EXPR);                                        \
            float top = patch[rowm + x];                                       \
            float bot = patch[rowp + x];                                       \
            float G = cnext - cprev;          /* 2*gx */                       \
            float H = bot - top;              /* 2*gy */                       \
            float mag = sqrtf(fmaf(G, G, fmaf(H, H, 4e-10f))) * (gy_t * gtab[x]); \
            float Gx = G + 2e-10f;                                             \
            float ax = fabsf(Gx), ay = fabsf(H);                               \
            float mn = fminf(ax, ay), mx = fmaxf(ax, ay);                      \
            float t1 = mn * __builtin_amdgcn_rcpf(fmaxf(mx, 1e-35f));          \
            float ss = t1 * t1;                                                \
            float u  = t1 * fmaf(ss, fmaf(ss, fmaf(ss, fmaf(ss, C4, C3), C2), C1), C0); \
            float A  = (ay > ax) ? 2.0f - u : u;                               \
            A = (Gx < 0.0f) ? 4.0f - A : A;                                    \
            A = (H  < 0.0f) ? -A : A;                                          \
            float ob = A + 8.0f;              /* in [4,12] */                  \
            float fl = truncf(ob);                                             \
            float fr = ob - fl;                                                \
            int b0 = ((int)fl) & 7;                                            \
            float w1 = fr * mag;                                               \
            float w0 = mag - w1;                                               \
            unsigned uq0 = (unsigned)fminf(w0 * QS, 16383.0f);                 \
            unsigned uq1 = (unsigned)fminf(w1 * QS, 16383.0f);                 \
            PW[PWIDX] = uq0 | (uq1 << 14) | ((unsigned)b0 << 28);              \
            cprev = ccur; ccur = cnext;                                        \
        }

        #pragma unroll
        for (int i = 0; i < 16; ++i) {
            PX1(x0 + i, patch[rowb + x + 1], pwb + i)
        }
        if (q == 3) {
            PX1(64, ccur, pwb + 16)     // right neighbor clamps to itself
        }
#undef PX1
    }
    __syncthreads();

    // zero S (aliases patch -- safe only after the barrier above)
    for (int k = tid; k < SSZ; k += 256) S[k] = 0.0f;
    __syncthreads();

    // ---- pass 2: item e = (row y, window j). Thread exclusively owns S row slots
    // S[(y+6)*SPIT + j*8 + k] -> plain read-fma-write, NO atomics.
    for (int e = tid; e < 260; e += 256) {
        const int y = e >> 2;
        const int j = e & 3;
        const unsigned long long* pw2 =
            (const unsigned long long*)&PW[y * PWP + (j << 4)];  // col 16j+t, t=0..25
        float* sb = &S[(y + 6) * SPIT + (j << 3)];

        #pragma unroll
        for (int th = 0; th < 13; ++th) {
            unsigned long long uu = pw2[th];
            #pragma unroll
            for (int h = 0; h < 2; ++h) {
                const int   t  = th * 2 + h;
                const float wq = (13.0f - fabsf((float)t - 12.5f)) *
                                 (1.0f / 13.0f) * (1.0f / QS);   // compile-time
                unsigned u = (unsigned)(uu >> (32 * h));
                float q0f = (float)(u & 0x3FFFu);
                float q1f = (float)((u >> 14) & 0x3FFFu);
                int   b0  = (int)(u >> 28);
                int   b1  = (b0 + 1) & 7;
                sb[b0] = fmaf(q0f, wq, sb[b0]);
                sb[b1] = fmaf(q1f, wq, sb[b1]);
            }
        }
    }
    __syncthreads();

    // ---- row pass: bin = k*16 + i*4 + j sums S[(i*16+t)*SPIT + j*8 + k], t=0..25
    if (tid < 128) {
        const int k  = tid >> 4;
        const int ii = (tid >> 2) & 3;
        const int j  = tid & 3;
        const int base = (ii * 16) * SPIT + (j << 3) + k;
        float v = 0.0f;
        #pragma unroll
        for (int t = 0; t < 26; ++t) {
            const float wy = (13.0f - fabsf((float)t - 12.5f)) * (1.0f / 13.0f);
            v += wy * S[base + t * SPIT];
        }
        fin[tid] = v;
    }
    __syncthreads();

    // first L2 norm
    if (tid < 64) {
        float sq = fin[tid] * fin[tid] + fin[tid + 64] * fin[tid + 64];
        #pragma unroll
        for (int off = 32; off > 0; off >>= 1) sq += __shfl_down(sq, off);
        if (tid == 0) redv[0] = sq;
    }
    __syncthreads();
    float inv1 = 1.0f / fmaxf(sqrtf(redv[0]), 1e-12f);
    if (tid < 128) {
        fin[tid] = fminf(fin[tid] * inv1, 0.2f);   // non-negative; clip hi only
    }
    __syncthreads();

    // second L2 norm
    if (tid < 64) {
        float sq = fin[tid] * fin[tid] + fin[tid + 64] * fin[tid + 64];
        #pragma unroll
        for (int off = 32; off > 0; off >>= 1) sq += __shfl_down(sq, off);
        if (tid == 0) redv[1] = sq;
    }
    __syncthreads();
    float inv2 = 1.0f / fmaxf(sqrtf(redv[1]), 1e-12f);
    if (tid < 128) {
        out[(size_t)s * 128 + tid] = fin[tid] * inv2;
    }
}

extern "C" void kernel_launch(void* const* d_in, const int* in_sizes, int n_in,
                              void* d_out, int out_size, void* d_ws, size_t ws_size,
                              hipStream_t stream) {
    const float* img = (const float*)d_in[0];
    float* out = (float*)d_out;
    const int B = in_sizes[0] / (3 * 520 * 520);
    const int nslices = B * 192;
    sift_desc_kernel<<<nslices, 256, 0, stream>>>(img, out);
}

// Round 6
// 100.270 us; speedup vs baseline: 4.5066x; 1.0304x over previous
//
#include <hip/hip_runtime.h>
#include <math.h>

#define PS     65
#define NPIX   (PS * PS)
#define PWP    75                 // PW pitch (odd: 11y mod 32 spreads banks, <=2-way)
#define SPIT   37                 // S pitch: 4 rings x 9 = 36 slots + 1 pad
#define SROWS  77                 // S rows: y+6 for y in [-6, 70] (pad rows zero)
#define SSZ    (SROWS * SPIT)     // 2849 <= NPIX, S aliases patch

// atan(t)*(4/pi) for t in [0,1], degree-9 odd minimax, |err|<=1.3e-5
#define C0  1.2730689f
#define C1 -0.4205505f
#define C2  0.2293627f
#define C3 -0.1083947f
#define C4  0.0265281f

#define QS  8388608.0f            // 2^23 fixed-point pack scale (cancels in L2 norms)

__global__ __launch_bounds__(256) void sift_desc_kernel(
        const float* __restrict__ img, float* __restrict__ out) {
    const int s   = blockIdx.x;     // slice index in (B, C, 8, 8) row-major
    const int tid = threadIdx.x;

    // decode slice -> (b, c, tile_i, tile_j)
    const int b   = s / 192;        // C*8*8 = 192
    const int rem = s - b * 192;
    const int c   = rem >> 6;
    const int t2  = rem & 63;
    const int pi  = t2 >> 3;
    const int pj  = t2 & 7;
    const float* src = img + ((size_t)((b * 3 + c) * 520 + pi * 65)) * 520 + pj * 65;

    __shared__ float patch[NPIX];                 // later aliased as S (SSZ < NPIX)
    __shared__ unsigned int PW[PS * PWP];
    __shared__ float gtab[PS];
    __shared__ float fin[128];
    __shared__ float redv[2];

    float* S = patch;   // reuse: patch is dead after pass 1 (barrier-separated)

    // phase 0: zero PW (pads must be 0), gaussian table, stage patch
    for (int k = tid; k < PS * PWP; k += 256) PW[k] = 0u;
    if (tid < PS) {
        float d = (float)(tid - 32);
        gtab[tid] = expf(-(d * d) * (1.0f / 4225.0f));   // sigma=65/sqrt2 -> 2s^2=4225
    }
    for (int p = tid; p < NPIX; p += 256) {
        int y = p / 65;
        int x = p - y * 65;
        patch[p] = src[y * 520 + x];
    }
    __syncthreads();

    // normalize gtab; fold sqrt(0.5) (gradient /2 factor, applied twice via gy*gx)
    if (tid < 64) {
        float v = gtab[tid] + ((tid == 0) ? gtab[64] : 0.0f);
        #pragma unroll
        for (int off = 32; off > 0; off >>= 1) v += __shfl_down(v, off);
        if (tid == 0) redv[0] = 0.70710678f / v;
    }
    __syncthreads();
    const float invZ = redv[0];
    if (tid < PS) gtab[tid] *= invZ;
    __syncthreads();

    // ---- pass 1: per-pixel math ONCE; item e = (row y, x-quarter q), sliding window
    for (int e = tid; e < 260; e += 256) {
        const int y  = e >> 2;
        const int q  = e & 3;
        const int x0 = q << 4;

        const int rowb = y * 65;
        const int rowm = (y > 0  ? y - 1 : 0)  * 65;
        const int rowp = (y < 64 ? y + 1 : 64) * 65;
        const float gy_t = gtab[y];
        const int pwb = y * PWP + 6 + x0;          // store at col x+6

        float cprev = patch[rowb + ((q == 0) ? 0 : x0 - 1)];
        float ccur  = patch[rowb + x0];

#define PX1(XEXPR, CNEXT_EXPR, PWIDX)                                          \
        {                                                                      \
            const int x = (XEXPR);                                             \
            float cnext = (CNEXT_EXPR);                                        \
            float top = patch[rowm + x];                                       \
            float bot = patch[rowp + x];                                       \
            float G = cnext - cprev;          /* 2*gx */                       \
            float H = bot - top;              /* 2*gy */                       \
            float mag = sqrtf(fmaf(G, G, fmaf(H, H, 4e-10f))) * (gy_t * gtab[x]); \
            float Gx = G + 2e-10f;                                             \
            float ax = fabsf(Gx), ay = fabsf(H);                               \
            float mn = fminf(ax, ay), mx = fmaxf(ax, ay);                      \
            float t1 = mn * __builtin_amdgcn_rcpf(fmaxf(mx, 1e-35f));          \
            float ss = t1 * t1;                                                \
            float u  = t1 * fmaf(ss, fmaf(ss, fmaf(ss, fmaf(ss, C4, C3), C2), C1), C0); \
            float A  = (ay > ax) ? 2.0f - u : u;                               \
            A = (Gx < 0.0f) ? 4.0f - A : A;                                    \
            A = (H  < 0.0f) ? -A : A;                                          \
            float ob = A + 8.0f;              /* in [4,12] */                  \
            float fl = truncf(ob);                                             \
            float fr = ob - fl;                                                \
            int b0 = ((int)fl) & 7;                                            \
            float w1 = fr * mag;                                               \
            float w0 = mag - w1;                                               \
            unsigned uq0 = (unsigned)fminf(w0 * QS, 16383.0f);                 \
            unsigned uq1 = (unsigned)fminf(w1 * QS, 16383.0f);                 \
            PW[PWIDX] = uq0 | (uq1 << 14) | ((unsigned)b0 << 28);              \
            cprev = ccur; ccur = cnext;                                        \
        }

        #pragma unroll
        for (int i = 0; i < 16; ++i) {
            PX1(x0 + i, patch[rowb + x + 1], pwb + i)
        }
        if (q == 3) {
            PX1(64, ccur, pwb + 16)     // right neighbor clamps to itself
        }
#undef PX1
    }
    __syncthreads();

    // zero S (aliases patch -- safe only after the barrier above)
    for (int k = tid; k < SSZ; k += 256) S[k] = 0.0f;
    __syncthreads();

    // ---- pass 2: item e = (row y, window j). Thread exclusively owns a 9-slot
    // ring S[(y+6)*SPIT + j*9 + (0..8)]; targets b0,b0+1 adjacent -> the
    // compiler merges each RMW into ds_read2_b32 + ds_write2_b32. No atomics.
    for (int e = tid; e < 260; e += 256) {
        const int y = e >> 2;
        const int j = e & 3;
        const unsigned int* pwrow = &PW[y * PWP + (j << 4)];  // col 16j+t, t=0..25
        float* ring = &S[(y + 6) * SPIT + j * 9];

        #pragma unroll
        for (int t = 0; t < 26; ++t) {
            const float wq = (13.0f - fabsf((float)t - 12.5f)) *
                             (1.0f / 13.0f) * (1.0f / QS);   // compile-time
            unsigned u = pwrow[t];
            float q0f = (float)(u & 0x3FFFu);
            float q1f = (float)((u >> 14) & 0x3FFFu);
            int   b0  = (int)(u >> 28);
            float lo  = ring[b0];
            float hi  = ring[b0 + 1];
            ring[b0]     = fmaf(q0f, wq, lo);
            ring[b0 + 1] = fmaf(q1f, wq, hi);
        }
    }
    __syncthreads();

    // fold ring slot 8 into slot 0 (bin 0 wrap)
    for (int k = tid; k < SROWS * 4; k += 256) {
        const int r = k >> 2;
        const int j = k & 3;
        const int o = r * SPIT + j * 9;
        S[o] += S[o + 8];
    }
    __syncthreads();

    // ---- row pass: bin = k*16 + ii*4 + j sums ring slot k over t=0..25
    if (tid < 128) {
        const int k  = tid >> 4;
        const int ii = (tid >> 2) & 3;
        const int j  = tid & 3;
        const int base = (ii * 16) * SPIT + j * 9 + k;
        float v = 0.0f;
        #pragma unroll
        for (int t = 0; t < 26; ++t) {
            const float wy = (13.0f - fabsf((float)t - 12.5f)) * (1.0f / 13.0f);
            v += wy * S[base + t * SPIT];
        }
        fin[tid] = v;
    }
    __syncthreads();

    // first L2 norm
    if (tid < 64) {
        float sq = fin[tid] * fin[tid] + fin[tid + 64] * fin[tid + 64];
        #pragma unroll
        for (int off = 32; off > 0; off >>= 1) sq += __shfl_down(sq, off);
        if (tid == 0) redv[0] = sq;
    }
    __syncthreads();
    float inv1 = 1.0f / fmaxf(sqrtf(redv[0]), 1e-12f);
    if (tid < 128) {
        fin[tid] = fminf(fin[tid] * inv1, 0.2f);   // non-negative; clip hi only
    }
    __syncthreads();

    // second L2 norm
    if (tid < 64) {
        float sq = fin[tid] * fin[tid] + fin[tid + 64] * fin[tid + 64];
        #pragma unroll
        for (int off = 32; off > 0; off >>= 1) sq += __shfl_down(sq, off);
        if (tid == 0) redv[1] = sq;
    }
    __syncthreads();
    float inv2 = 1.0f / fmaxf(sqrtf(redv[1]), 1e-12f);
    if (tid < 128) {
        out[(size_t)s * 128 + tid] = fin[tid] * inv2;
    }
}

extern "C" void kernel_launch(void* const* d_in, const int* in_sizes, int n_in,
                              void* d_out, int out_size, void* d_ws, size_t ws_size,
                              hipStream_t stream) {
    const float* img = (const float*)d_in[0];
    float* out = (float*)d_out;
    const int B = in_sizes[0] / (3 * 520 * 520);
    const int nslices = B * 192;
    sift_desc_kernel<<<nslices, 256, 0, stream>>>(img, out);
}